// Round 6
// baseline (1670.277 us; speedup 1.0000x reference)
//
#include <hip/hip_runtime.h>

#define N_IN 200000
#define N_OUT 200000
#define K_VOL 27
#define M_PAIRS 100000
#define C_IN 64
#define C_OUT 64

// output privatization: each block owns RROWS output rows, accumulates in LDS fp32
#define RROWS 64
#define RSHIFT 6
#define NRANGE (N_OUT / RROWS)          // 3125 (exact)
#define NBUCKET (NRANGE * K_VOL)        // 84375 (bucket = range*27 + k, range-major)
#define NREC (K_VOL * M_PAIRS)          // 2,700,000
#define NRECPAD (NREC + 16 * NBUCKET)   // 4,050,000 words (buckets padded to x16)

#define ACC_PAD 68                      // acc row stride in floats (272B) spreads ds_add banks
#define NWAVES 4
#define NTHREADS 256
#define MAXT 256                        // tile table cap (expected ~135/block); writes guarded
#define NSLICE 16
#define MSLICE (M_PAIRS / NSLICE)       // 6250
#define NCOUNTB (NSLICE * K_VOL)        // 432 count-role blocks in prep
#define NCVTB 1024                      // cvt/fill-role blocks in prep

typedef __attribute__((ext_vector_type(4))) float floatx4;
typedef __attribute__((ext_vector_type(8))) short shortx8;

static __device__ __forceinline__ ushort f32_to_bf16(float f) {
    union { float f; unsigned int u; } x; x.f = f;
    unsigned int u = x.u;
    u += 0x7FFFu + ((u >> 16) & 1u);   // round-to-nearest-even
    return (ushort)(u >> 16);
}

// native LDS fp32 add (HIP atomicAdd on shared float expands to a CAS loop because
// default denormal mode forbids the native lowering). Completion is guaranteed by the
// explicit lgkmcnt(0) drain before the final barrier.
static __device__ __forceinline__ void ds_addf(unsigned addr32, float v) {
    asm volatile("ds_add_f32 %0, %1" :: "v"(addr32), "v"(v) : "memory");
}

// MFMA-dst read hazard fence (R3/R4 bug theory): inline-asm consumers of MFMA results
// are not reliably covered by the compiler's hazard-nop insertion. This asm READS the 4
// acc values (data dep -> must follow the MFMAs) and burns 16 cycles; the following
// volatile ds_adds cannot be reordered above it -> guaranteed >= 16 cycles spacing
// (documented worst-case MFMA-dst->VALU/DS-read requirement is <= 11).
static __device__ __forceinline__ void mfma_fence(floatx4 a) {
    asm volatile("s_nop 7\n\ts_nop 7" :: "v"(a[0]), "v"(a[1]), "v"(a[2]), "v"(a[3]));
}

// Fused prepass: blocks [0,432) = per-(slice,k) LDS histogram -> global counts;
// blocks [432,1456) = grid-stride cvt_feats + cvt_wt(transpose) + records sentinel-fill.
__global__ void prep_kernel(const float* __restrict__ in_feats,
                            const float* __restrict__ w,
                            const int* __restrict__ omap,
                            ushort* __restrict__ feats_bf,
                            ushort* __restrict__ wt_bf,
                            unsigned int* __restrict__ counts,
                            uint4* __restrict__ records4) {
    __shared__ unsigned int hist[NRANGE];   // 12.5 KB (unused by cvt-role blocks)
    const int bx  = blockIdx.x;
    const int tid = threadIdx.x;

    if (bx < NCOUNTB) {
        const int k  = bx / NSLICE;
        const int m0 = (bx % NSLICE) * MSLICE;
        const int kM = k * M_PAIRS;
        for (int b = tid; b < NRANGE; b += NTHREADS) hist[b] = 0;
        __syncthreads();
        for (int j = tid; j < MSLICE; j += NTHREADS) {
            int o = omap[kM + m0 + j];
            atomicAdd(&hist[o >> RSHIFT], 1u);           // native ds_add_rtn_u32 (int)
        }
        __syncthreads();
        for (int b = tid; b < NRANGE; b += NTHREADS) {
            unsigned int c = hist[b];
            if (c) atomicAdd(&counts[b * K_VOL + k], c); // <=16-way contention
        }
    } else {
        const int g0 = (bx - NCOUNTB) * NTHREADS + tid;
        const int GS = NCVTB * NTHREADS;                 // 262144
        const int n4 = N_IN * C_IN / 4;                  // 3,200,000
        for (int i = g0; i < n4; i += GS) {
            float4 v = ((const float4*)in_feats)[i];
            ushort4 o;
            o.x = f32_to_bf16(v.x); o.y = f32_to_bf16(v.y);
            o.z = f32_to_bf16(v.z); o.w = f32_to_bf16(v.w);
            ((ushort4*)feats_bf)[i] = o;
        }
        for (int idx = g0; idx < K_VOL * C_IN * C_OUT; idx += GS) {
            int k = idx >> 12; int rem = idx & 4095;
            int c = rem >> 6;  int o = rem & 63;
            wt_bf[(k << 12) + (o << 6) + c] = f32_to_bf16(w[idx]);
        }
        const uint4 s4 = make_uint4(0x80808080u, 0x80808080u, 0x80808080u, 0x80808080u);
        for (int i = g0; i < NRECPAD / 4; i += GS) records4[i] = s4;   // sentinel: bit31 set
    }
}

// Exclusive scan of 84375 bucket counts, each padded to x16 (R2-proven structure).
__global__ void scan_kernel(const unsigned int* __restrict__ counts,
                            unsigned int* __restrict__ offsets,
                            unsigned int* __restrict__ cursor) {
    __shared__ unsigned int part[1024];
    const int tid = threadIdx.x;
    const int CH  = (NBUCKET + 1023) / 1024;   // 83
    const int b0  = tid * CH;
    unsigned int s = 0;
    for (int j = 0; j < CH; ++j) {
        int b = b0 + j;
        if (b < NBUCKET) s += (counts[b] + 15u) & ~15u;
    }
    part[tid] = s;
    __syncthreads();
    for (int d = 1; d < 1024; d <<= 1) {
        unsigned int v = (tid >= d) ? part[tid - d] : 0u;
        __syncthreads();
        part[tid] += v;
        __syncthreads();
    }
    unsigned int run = (tid > 0) ? part[tid - 1] : 0u;
    for (int j = 0; j < CH; ++j) {
        int b = b0 + j;
        if (b < NBUCKET) {
            offsets[b] = run;
            cursor[b]  = run;
            run += (counts[b] + 15u) & ~15u;
        }
    }
    if (tid == 1023) offsets[NBUCKET] = run;
}

// Two-pass block scatter (R2-proven): LDS hist -> one reservation atomic per (block,bin)
// -> record writes via atomicExch (cross-XCD word writes resolve at the coherence point).
__global__ void scatter_kernel(const int* __restrict__ imap, const int* __restrict__ omap,
                               unsigned int* __restrict__ cursor, unsigned int* __restrict__ records) {
    __shared__ unsigned int hist[NRANGE];     // 12.5 KB
    __shared__ unsigned int base_s[NRANGE];   // 12.5 KB
    const int k   = blockIdx.y;
    const int tid = threadIdx.x;
    const int m0  = blockIdx.x * MSLICE;
    const int kM  = k * M_PAIRS;

    for (int b = tid; b < NRANGE; b += NTHREADS) hist[b] = 0;
    __syncthreads();
    for (int j = tid; j < MSLICE; j += NTHREADS) {
        int o = omap[kM + m0 + j];
        atomicAdd(&hist[o >> RSHIFT], 1u);
    }
    __syncthreads();
    for (int b = tid; b < NRANGE; b += NTHREADS) {
        unsigned int c = hist[b];
        base_s[b] = c ? atomicAdd(&cursor[b * K_VOL + k], c) : 0u;
    }
    __syncthreads();
    for (int b = tid; b < NRANGE; b += NTHREADS) hist[b] = 0;   // reuse as local cursor
    __syncthreads();
    for (int j = tid; j < MSLICE; j += NTHREADS) {
        int o = omap[kM + m0 + j];
        int r = o >> RSHIFT;
        unsigned int loc = atomicAdd(&hist[r], 1u);
        unsigned int g   = (unsigned int)imap[kM + m0 + j];
        atomicExch(&records[base_s[r] + loc], g | ((unsigned int)(o & (RROWS - 1)) << 18));
    }
}

// Phase B: wave-autonomous 16-record tiles, depth-2/1 software pipeline,
// native ds_add_f32 into the block's private (64+1)x64 fp32 LDS accumulator.
__launch_bounds__(NTHREADS, 4)
__global__ void spconv_kernel(const ushort* __restrict__ feats,    // [N_IN][64] bf16
                              const ushort* __restrict__ wt,       // [K][64 o][64 c] bf16
                              const unsigned int* __restrict__ offsets,
                              const unsigned int* __restrict__ records,
                              const float* __restrict__ bias,
                              float* __restrict__ out) {
    __shared__ __align__(16) float accs[(RROWS + 1) * ACC_PAD];  // 17,680 B (+1 dummy row)
    __shared__ unsigned int tile_s[MAXT];                        // t | (k<<24)
    __shared__ int ntiles_s;

    const int tid = threadIdx.x;
    const int bx  = blockIdx.x;

    for (int idx = tid; idx < ((RROWS + 1) * ACC_PAD) / 4; idx += NTHREADS)
        ((float4*)accs)[idx] = make_float4(0.f, 0.f, 0.f, 0.f);

    // wave 0 builds the tile table (k ascending; offsets are x16-padded so nt is exact)
    if (tid < 64) {
        int kk = tid;
        int nt = 0; unsigned int beg = 0;
        if (kk < K_VOL) {
            beg = offsets[bx * K_VOL + kk];
            nt  = (int)((offsets[bx * K_VOL + kk + 1] - beg) >> 4);
        }
        int x = nt;
        #pragma unroll
        for (int d = 1; d < 32; d <<= 1) {    // 5 steps: exact prefix for lanes < 32 (k < 27)
            int y = __shfl_up(x, d);
            if (tid >= d) x += y;
        }
        int base = x - nt;
        for (int j = 0; j < nt; ++j) {
            int e = base + j;
            if (e < MAXT) tile_s[e] = (beg + (unsigned int)(j << 4)) | ((unsigned int)kk << 24);
        }
        if (kk == K_VOL - 1) ntiles_s = (x < MAXT) ? x : MAXT;
    }
    __syncthreads();

    const int wave = tid >> 6;
    const int lane = tid & 63;
    const int quad = lane >> 4;
    const int l16  = lane & 15;
    const unsigned int acc_base = (unsigned int)(unsigned long long)&accs[0];

    const int ntiles = ntiles_s;
    const int i0 = (ntiles * wave) / NWAVES;
    const int i1 = (ntiles * (wave + 1)) / NWAVES;

    if (i0 < i1) {
        int kcur = -1;
        shortx8 bwA0, bwA1, bwB0, bwB1, bwC0, bwC1, bwD0, bwD1;  // named -> registers

        unsigned int e_a = tile_s[i0];
        unsigned int t_a = e_a & 0xFFFFFFu; int k_a = (int)(e_a >> 24);
        unsigned int rec_a = records[t_a + l16];
        int4 rr_a = *(const int4*)&records[t_a + (quad << 2)];   // t % 16 == 0 -> aligned

        const int ib = (i0 + 1 < i1) ? i0 + 1 : i0;
        unsigned int e_b = tile_s[ib];
        unsigned int t_b = e_b & 0xFFFFFFu; int k_b = (int)(e_b >> 24);
        unsigned int rec_b = records[t_b + l16];
        int4 rr_b = *(const int4*)&records[t_b + (quad << 2)];

        unsigned int ga = (rec_a & 0x3FFFFu) << 6;
        shortx8 a0 = *(const shortx8*)&feats[ga + quad * 8];
        shortx8 a1 = *(const shortx8*)&feats[ga + 32 + quad * 8];

        for (int i = i0; i < i1; ++i) {
            const int ic = (i + 2 < i1) ? i + 2 : i1 - 1;        // stage C records (tile i+2)
            unsigned int e_c = tile_s[ic];
            unsigned int t_c = e_c & 0xFFFFFFu; int k_c = (int)(e_c >> 24);
            unsigned int rec_c = records[t_c + l16];
            int4 rr_c = *(const int4*)&records[t_c + (quad << 2)];
            unsigned int gb = (rec_b & 0x3FFFFu) << 6;           // stage B A-frags (tile i+1)
            shortx8 na0 = *(const shortx8*)&feats[gb + quad * 8];
            shortx8 na1 = *(const shortx8*)&feats[gb + 32 + quad * 8];

            if (k_a != kcur) {          // wave-uniform (tiles k-ascending, chunk contiguous)
                kcur = k_a;
                const ushort* wp = &wt[(kcur << 12) + l16 * 64 + quad * 8];
                bwA0 = *(const shortx8*)(wp);            bwA1 = *(const shortx8*)(wp + 32);
                bwB0 = *(const shortx8*)(wp + 16 * 64);  bwB1 = *(const shortx8*)(wp + 16 * 64 + 32);
                bwC0 = *(const shortx8*)(wp + 32 * 64);  bwC1 = *(const shortx8*)(wp + 32 * 64 + 32);
                bwD0 = *(const shortx8*)(wp + 48 * 64);  bwD1 = *(const shortx8*)(wp + 48 * 64 + 32);
            }

            // C rows (quad*4 + r); sentinel records (bit31) -> dummy row RROWS (discarded)
            const int ra = (rr_a.x < 0) ? RROWS : ((rr_a.x >> 18) & (RROWS - 1));
            const int rb = (rr_a.y < 0) ? RROWS : ((rr_a.y >> 18) & (RROWS - 1));
            const int rc = (rr_a.z < 0) ? RROWS : ((rr_a.z >> 18) & (RROWS - 1));
            const int rd = (rr_a.w < 0) ? RROWS : ((rr_a.w >> 18) & (RROWS - 1));
            const unsigned int ad0 = acc_base + (unsigned int)(ra * (ACC_PAD * 4));
            const unsigned int ad1 = acc_base + (unsigned int)(rb * (ACC_PAD * 4));
            const unsigned int ad2 = acc_base + (unsigned int)(rc * (ACC_PAD * 4));
            const unsigned int ad3 = acc_base + (unsigned int)(rd * (ACC_PAD * 4));

            {
                floatx4 acc = {0.f, 0.f, 0.f, 0.f};
                acc = __builtin_amdgcn_mfma_f32_16x16x32_bf16(a0, bwA0, acc, 0, 0, 0);
                acc = __builtin_amdgcn_mfma_f32_16x16x32_bf16(a1, bwA1, acc, 0, 0, 0);
                mfma_fence(acc);                              // MFMA->DS read hazard spacing
                unsigned int co = (unsigned int)(l16 << 2);
                ds_addf(ad0 + co, acc[0]); ds_addf(ad1 + co, acc[1]);
                ds_addf(ad2 + co, acc[2]); ds_addf(ad3 + co, acc[3]);
            }
            {
                floatx4 acc = {0.f, 0.f, 0.f, 0.f};
                acc = __builtin_amdgcn_mfma_f32_16x16x32_bf16(a0, bwB0, acc, 0, 0, 0);
                acc = __builtin_amdgcn_mfma_f32_16x16x32_bf16(a1, bwB1, acc, 0, 0, 0);
                mfma_fence(acc);
                unsigned int co = (unsigned int)((16 + l16) << 2);
                ds_addf(ad0 + co, acc[0]); ds_addf(ad1 + co, acc[1]);
                ds_addf(ad2 + co, acc[2]); ds_addf(ad3 + co, acc[3]);
            }
            {
                floatx4 acc = {0.f, 0.f, 0.f, 0.f};
                acc = __builtin_amdgcn_mfma_f32_16x16x32_bf16(a0, bwC0, acc, 0, 0, 0);
                acc = __builtin_amdgcn_mfma_f32_16x16x32_bf16(a1, bwC1, acc, 0, 0, 0);
                mfma_fence(acc);
                unsigned int co = (unsigned int)((32 + l16) << 2);
                ds_addf(ad0 + co, acc[0]); ds_addf(ad1 + co, acc[1]);
                ds_addf(ad2 + co, acc[2]); ds_addf(ad3 + co, acc[3]);
            }
            {
                floatx4 acc = {0.f, 0.f, 0.f, 0.f};
                acc = __builtin_amdgcn_mfma_f32_16x16x32_bf16(a0, bwD0, acc, 0, 0, 0);
                acc = __builtin_amdgcn_mfma_f32_16x16x32_bf16(a1, bwD1, acc, 0, 0, 0);
                mfma_fence(acc);
                unsigned int co = (unsigned int)((48 + l16) << 2);
                ds_addf(ad0 + co, acc[0]); ds_addf(ad1 + co, acc[1]);
                ds_addf(ad2 + co, acc[2]); ds_addf(ad3 + co, acc[3]);
            }

            rec_a = rec_b; rr_a = rr_b; k_a = k_b;     // rotate pipeline
            rec_b = rec_c; rr_b = rr_c; k_b = k_c;
            a0 = na0; a1 = na1;
        }
    }

    // drain the inline-asm ds_add ops (invisible to the compiler's pre-barrier waitcnt)
    asm volatile("s_waitcnt lgkmcnt(0)" ::: "memory");
    __builtin_amdgcn_sched_barrier(0);
    __syncthreads();

    // write out 64 rows x 64 ch, bias fused, each output line written exactly once
    const int r0 = bx * RROWS;
    #pragma unroll
    for (int it = 0; it < (RROWS * 16) / NTHREADS; ++it) {
        int idx  = tid + it * NTHREADS;      // 0..1023 float4 slots
        int row  = idx >> 4;
        int c4   = idx & 15;
        int orow = r0 + row;
        if (orow < N_OUT) {
            float4 v = *(float4*)&accs[row * ACC_PAD + c4 * 4];
            const float4 bb = *(const float4*)&bias[c4 * 4];
            v.x += bb.x; v.y += bb.y; v.z += bb.z; v.w += bb.w;
            *(float4*)&out[(orow << 6) + c4 * 4] = v;
        }
    }
}

extern "C" void kernel_launch(void* const* d_in, const int* in_sizes, int n_in,
                              void* d_out, int out_size, void* d_ws, size_t ws_size,
                              hipStream_t stream) {
    const float* in_feats = (const float*)d_in[0];
    const float* kernelw  = (const float*)d_in[1];
    const float* bias     = (const float*)d_in[2];
    const int*   imap     = (const int*)d_in[3];
    const int*   omap     = (const int*)d_in[4];
    float* out = (float*)d_out;

    char* p = (char*)d_ws;
    ushort* feats_bf = (ushort*)p;  p += (size_t)N_IN * C_IN * 2;                        // 25.6 MB
    ushort* wt_bf    = (ushort*)p;  p += (size_t)K_VOL * C_IN * C_OUT * 2;               // 216 KB
    unsigned int* counts  = (unsigned int*)p;  p += (((size_t)(NBUCKET + 1) * 4 + 63) & ~(size_t)63);
    unsigned int* offsets = (unsigned int*)p;  p += (((size_t)(NBUCKET + 1) * 4 + 63) & ~(size_t)63);
    unsigned int* cursor  = (unsigned int*)p;  p += (((size_t)(NBUCKET + 1) * 4 + 63) & ~(size_t)63);
    unsigned int* records = (unsigned int*)p;  p += (size_t)NRECPAD * 4;                 // 16.2 MB

    hipMemsetAsync(counts, 0, (size_t)NBUCKET * 4, stream);

    prep_kernel<<<NCOUNTB + NCVTB, NTHREADS, 0, stream>>>(
        in_feats, kernelw, omap, feats_bf, wt_bf, counts, (uint4*)records);
    scan_kernel<<<1, 1024, 0, stream>>>(counts, offsets, cursor);
    dim3 gmap(NSLICE, K_VOL);
    scatter_kernel<<<gmap, NTHREADS, 0, stream>>>(imap, omap, cursor, records);
    spconv_kernel<<<NRANGE, NTHREADS, 0, stream>>>(feats_bf, wt_bf, offsets, records, bias, out);
}

// Round 7
// 1561.396 us; speedup vs baseline: 1.0697x; 1.0697x over previous
//
#include <hip/hip_runtime.h>

#define N_IN 200000
#define N_OUT 200000
#define K_VOL 27
#define M_PAIRS 100000
#define C_IN 64
#define C_OUT 64

// output privatization: each block owns RROWS output rows, accumulates in LDS fp32
#define RROWS 64
#define RSHIFT 6
#define NRANGE (N_OUT / RROWS)        // 3125 (exact)
#define NBUCKET (NRANGE * K_VOL)      // 84375 (bucket = range*27 + k)
#define CAP 96                        // fixed bucket capacity; Poisson(32) -> P(any>96) ~ 1e-14
#define ACC_PAD 68                    // acc row stride (272B), spreads ds_add banks
#define LDS_PAD 72                    // A-tile row stride (144B = 9x16B): aligned, de-aliased
#define NTHREADS 256
#define MAXG 176                      // ngroups <= 27 * ceil(96/16) = 162

typedef __attribute__((ext_vector_type(4))) float floatx4;
typedef __attribute__((ext_vector_type(8))) short shortx8;

static __device__ __forceinline__ ushort f32_to_bf16(float f) {
    union { float f; unsigned int u; } x; x.f = f;
    unsigned int u = x.u;
    u += 0x7FFFu + ((u >> 16) & 1u);   // round-to-nearest-even
    return (ushort)(u >> 16);
}

// native LDS fp32 add; completion guaranteed by explicit lgkmcnt(0) drain before the
// final barrier. (R6-proven correct in combination with mfma_fence.)
static __device__ __forceinline__ void ds_addf(unsigned addr32, float v) {
    asm volatile("ds_add_f32 %0, %1" :: "v"(addr32), "v"(v) : "memory");
}

// MFMA-dst -> inline-asm-DS read hazard spacing (R6-proven).
static __device__ __forceinline__ void mfma_fence(floatx4 a) {
    asm volatile("s_nop 7\n\ts_nop 7" :: "v"(a[0]), "v"(a[1]), "v"(a[2]), "v"(a[3]));
}

// grid-stride fp32->bf16 convert: feats + transposed weights
__global__ void cvt_kernel(const float* __restrict__ in_feats, const float* __restrict__ w,
                           ushort* __restrict__ feats_bf, ushort* __restrict__ wt_bf) {
    const int g0 = blockIdx.x * blockDim.x + threadIdx.x;
    const int GS = gridDim.x * blockDim.x;
    const int n4 = N_IN * C_IN / 4;
    for (int i = g0; i < n4; i += GS) {
        float4 v = ((const float4*)in_feats)[i];
        ushort4 o;
        o.x = f32_to_bf16(v.x); o.y = f32_to_bf16(v.y);
        o.z = f32_to_bf16(v.z); o.w = f32_to_bf16(v.w);
        ((ushort4*)feats_bf)[i] = o;
    }
    for (int idx = g0; idx < K_VOL * C_IN * C_OUT; idx += GS) {
        int k = idx >> 12; int rem = idx & 4095;
        int c = rem >> 6;  int o = rem & 63;
        wt_bf[(k << 12) + (o << 6) + c] = f32_to_bf16(w[idx]);
    }
}

// direct reservation scatter: one global atomicAdd (position) + atomicExch (payload,
// R2-proven cross-XCD-safe) per pair. cursor[] doubles as the per-bucket count.
__global__ void scatter_kernel(const int* __restrict__ imap, const int* __restrict__ omap,
                               unsigned int* __restrict__ cursor, unsigned int* __restrict__ records) {
    int m = blockIdx.x * NTHREADS + threadIdx.x;
    if (m >= M_PAIRS) return;
    const int k = blockIdx.y;
    const int o = omap[k * M_PAIRS + m];
    const int b = (o >> RSHIFT) * K_VOL + k;
    unsigned int pos = atomicAdd(&cursor[b], 1u);
    if (pos < CAP) {
        unsigned int g = (unsigned int)imap[k * M_PAIRS + m];
        atomicExch(&records[(unsigned int)b * CAP + pos], g | ((unsigned int)(o & (RROWS - 1)) << 18));
    }
}

// Phase B: per range-block, double-buffered cooperative staging of 64-record chunks
// (R0/R1-proven access pattern) + per-wave 16x64x64 MFMA + native ds_add_f32 into the
// block's private (64+1)x64 fp32 accumulator (R6-proven), one barrier per chunk.
__launch_bounds__(NTHREADS, 4)
__global__ void spconv_kernel(const ushort* __restrict__ feats,    // [N_IN][64] bf16
                              const ushort* __restrict__ wt,       // [K][64 o][64 c] bf16
                              const unsigned int* __restrict__ cursor,   // per-bucket counts
                              const unsigned int* __restrict__ records,  // [NBUCKET][CAP]
                              const float* __restrict__ bias,
                              float* __restrict__ out) {
    __shared__ __align__(16) float  accs[(RROWS + 1) * ACC_PAD];   // 17,680 B (+1 dummy row)
    __shared__ __align__(16) ushort Abuf[2][RROWS * LDS_PAD];      // 2 x 9,216 B
    __shared__ unsigned int  gt_s[MAXG];    // group start word-index in records
    __shared__ unsigned char gk_s[MAXG];    // group kernel-offset
    __shared__ unsigned char gv_s[MAXG];    // valid rows in group (1..16)
    __shared__ int ngroups_s;

    const int tid = threadIdx.x;
    const int bx  = blockIdx.x;

    for (int idx = tid; idx < ((RROWS + 1) * ACC_PAD) / 4; idx += NTHREADS)
        ((float4*)accs)[idx] = make_float4(0.f, 0.f, 0.f, 0.f);

    // wave 0 builds the group table (k ascending; groups are 16-padded -> single-k each)
    if (tid < 64) {
        int kk = tid;
        int nt = 0; unsigned int cnt = 0, base = 0;
        if (kk < K_VOL) {
            cnt = cursor[bx * K_VOL + kk];
            if (cnt > CAP) cnt = CAP;
            nt   = (int)((cnt + 15u) >> 4);
            base = (unsigned int)(bx * K_VOL + kk) * CAP;
        }
        int x = nt;
        #pragma unroll
        for (int d = 1; d < 32; d <<= 1) {
            int y = __shfl_up(x, d);
            if (tid >= d) x += y;
        }
        int gb = x - nt;
        for (int j = 0; j < nt; ++j) {
            int e = gb + j;
            if (e < MAXG) {
                gt_s[e] = base + (unsigned int)(j << 4);
                gk_s[e] = (unsigned char)kk;
                gv_s[e] = (unsigned char)((j == nt - 1) ? (cnt - (unsigned int)(j << 4)) : 16u);
            }
        }
        if (kk == K_VOL - 1) ngroups_s = (x < MAXG) ? x : MAXG;
    }
    __syncthreads();

    const int ngroups = ngroups_s;
    const int nchunks = (ngroups + 3) >> 2;        // 4 groups (64 rows) per chunk

    const int wave = tid >> 6;
    const int lane = tid & 63;
    const int quad = lane >> 4;
    const int l16  = lane & 15;
    const unsigned int acc_base = (unsigned int)(unsigned long long)&accs[0];

    // staging map: thread stages rows row0 and row0+32 of the chunk, 16B at column ch0*8
    const int row0 = tid >> 3;        // 0..31
    const int row1 = row0 + 32;       // 32..63
    const int ch0  = tid & 7;

    // prologue: stage chunk 0 into buf 0
    if (nchunks > 0) {
        int gA = row0 >> 4;           // 0..1
        if (gA < ngroups) {
            unsigned int rec = records[gt_s[gA] + (row0 & 15)];
            shortx8 v = *(const shortx8*)&feats[((rec & 0x3FFFFu) << 6) + ch0 * 8];
            *(shortx8*)&Abuf[0][row0 * LDS_PAD + ch0 * 8] = v;
        }
        int gB = row1 >> 4;           // 2..3
        if (gB < ngroups) {
            unsigned int rec = records[gt_s[gB] + (row1 & 15)];
            shortx8 v = *(const shortx8*)&feats[((rec & 0x3FFFFu) << 6) + ch0 * 8];
            *(shortx8*)&Abuf[0][row1 * LDS_PAD + ch0 * 8] = v;
        }
    }
    __syncthreads();

    int kcur = -1;
    shortx8 bwA0, bwA1, bwB0, bwB1, bwC0, bwC1, bwD0, bwD1;

    for (int cj = 0; cj < nchunks; ++cj) {
        const int cur = cj & 1, nxt = cur ^ 1;

        // (a) issue next chunk's gather loads early (T14 async split: write after compute)
        shortx8 n0, n1; bool h0 = false, h1 = false;
        if (cj + 1 < nchunks) {
            int gA = (cj + 1) * 4 + (row0 >> 4);
            if (gA < ngroups) {
                unsigned int rec = records[gt_s[gA] + (row0 & 15)];
                n0 = *(const shortx8*)&feats[((rec & 0x3FFFFu) << 6) + ch0 * 8];
                h0 = true;
            }
            int gB = (cj + 1) * 4 + (row1 >> 4);
            if (gB < ngroups) {
                unsigned int rec = records[gt_s[gB] + (row1 & 15)];
                n1 = *(const shortx8*)&feats[((rec & 0x3FFFFu) << 6) + ch0 * 8];
                h1 = true;
            }
        }

        // (b) compute this chunk: wave handles group cj*4 + wave (wave-uniform branch)
        const int gidx = cj * 4 + wave;
        if (gidx < ngroups) {
            const int k = (int)gk_s[gidx];
            if (k != kcur) {
                kcur = k;
                const ushort* wp = &wt[(kcur << 12) + l16 * 64 + quad * 8];
                bwA0 = *(const shortx8*)(wp);            bwA1 = *(const shortx8*)(wp + 32);
                bwB0 = *(const shortx8*)(wp + 16 * 64);  bwB1 = *(const shortx8*)(wp + 16 * 64 + 32);
                bwC0 = *(const shortx8*)(wp + 32 * 64);  bwC1 = *(const shortx8*)(wp + 32 * 64 + 32);
                bwD0 = *(const shortx8*)(wp + 48 * 64);  bwD1 = *(const shortx8*)(wp + 48 * 64 + 32);
            }
            const unsigned int t = gt_s[gidx];
            const int4 rr = *(const int4*)&records[t + (quad << 2)];   // t % 4 == 0 -> 16B aligned
            const int vld = (int)gv_s[gidx];

            const ushort* ap = &Abuf[cur][(wave * 16 + l16) * LDS_PAD];
            const shortx8 a0 = *(const shortx8*)&ap[quad * 8];
            const shortx8 a1 = *(const shortx8*)&ap[32 + quad * 8];

            // C rows = quad*4 + r; rows past the group's valid count -> dummy row RROWS
            const int q4 = quad << 2;
            const int ra = (q4 + 0 < vld) ? ((rr.x >> 18) & (RROWS - 1)) : RROWS;
            const int rb = (q4 + 1 < vld) ? ((rr.y >> 18) & (RROWS - 1)) : RROWS;
            const int rc = (q4 + 2 < vld) ? ((rr.z >> 18) & (RROWS - 1)) : RROWS;
            const int rd = (q4 + 3 < vld) ? ((rr.w >> 18) & (RROWS - 1)) : RROWS;
            const unsigned int ad0 = acc_base + (unsigned int)(ra * (ACC_PAD * 4));
            const unsigned int ad1 = acc_base + (unsigned int)(rb * (ACC_PAD * 4));
            const unsigned int ad2 = acc_base + (unsigned int)(rc * (ACC_PAD * 4));
            const unsigned int ad3 = acc_base + (unsigned int)(rd * (ACC_PAD * 4));

            {
                floatx4 acc = {0.f, 0.f, 0.f, 0.f};
                acc = __builtin_amdgcn_mfma_f32_16x16x32_bf16(a0, bwA0, acc, 0, 0, 0);
                acc = __builtin_amdgcn_mfma_f32_16x16x32_bf16(a1, bwA1, acc, 0, 0, 0);
                mfma_fence(acc);
                unsigned int co = (unsigned int)(l16 << 2);
                ds_addf(ad0 + co, acc[0]); ds_addf(ad1 + co, acc[1]);
                ds_addf(ad2 + co, acc[2]); ds_addf(ad3 + co, acc[3]);
            }
            {
                floatx4 acc = {0.f, 0.f, 0.f, 0.f};
                acc = __builtin_amdgcn_mfma_f32_16x16x32_bf16(a0, bwB0, acc, 0, 0, 0);
                acc = __builtin_amdgcn_mfma_f32_16x16x32_bf16(a1, bwB1, acc, 0, 0, 0);
                mfma_fence(acc);
                unsigned int co = (unsigned int)((16 + l16) << 2);
                ds_addf(ad0 + co, acc[0]); ds_addf(ad1 + co, acc[1]);
                ds_addf(ad2 + co, acc[2]); ds_addf(ad3 + co, acc[3]);
            }
            {
                floatx4 acc = {0.f, 0.f, 0.f, 0.f};
                acc = __builtin_amdgcn_mfma_f32_16x16x32_bf16(a0, bwC0, acc, 0, 0, 0);
                acc = __builtin_amdgcn_mfma_f32_16x16x32_bf16(a1, bwC1, acc, 0, 0, 0);
                mfma_fence(acc);
                unsigned int co = (unsigned int)((32 + l16) << 2);
                ds_addf(ad0 + co, acc[0]); ds_addf(ad1 + co, acc[1]);
                ds_addf(ad2 + co, acc[2]); ds_addf(ad3 + co, acc[3]);
            }
            {
                floatx4 acc = {0.f, 0.f, 0.f, 0.f};
                acc = __builtin_amdgcn_mfma_f32_16x16x32_bf16(a0, bwD0, acc, 0, 0, 0);
                acc = __builtin_amdgcn_mfma_f32_16x16x32_bf16(a1, bwD1, acc, 0, 0, 0);
                mfma_fence(acc);
                unsigned int co = (unsigned int)((48 + l16) << 2);
                ds_addf(ad0 + co, acc[0]); ds_addf(ad1 + co, acc[1]);
                ds_addf(ad2 + co, acc[2]); ds_addf(ad3 + co, acc[3]);
            }
        }

        // (c) write the prefetched chunk into the other buffer, then one barrier
        if (h0) *(shortx8*)&Abuf[nxt][row0 * LDS_PAD + ch0 * 8] = n0;
        if (h1) *(shortx8*)&Abuf[nxt][row1 * LDS_PAD + ch0 * 8] = n1;
        __syncthreads();
    }

    // drain the inline-asm ds_add ops (invisible to the compiler's pre-barrier waitcnt)
    asm volatile("s_waitcnt lgkmcnt(0)" ::: "memory");
    __builtin_amdgcn_sched_barrier(0);
    __syncthreads();

    // write out 64 rows x 64 ch, bias fused, each output line written exactly once
    const int r0 = bx * RROWS;
    #pragma unroll
    for (int it = 0; it < (RROWS * 16) / NTHREADS; ++it) {
        int idx  = tid + it * NTHREADS;      // 0..1023 float4 slots
        int row  = idx >> 4;
        int c4   = idx & 15;
        int orow = r0 + row;
        if (orow < N_OUT) {
            float4 v = *(float4*)&accs[row * ACC_PAD + c4 * 4];
            const float4 bb = *(const float4*)&bias[c4 * 4];
            v.x += bb.x; v.y += bb.y; v.z += bb.z; v.w += bb.w;
            *(float4*)&out[(orow << 6) + c4 * 4] = v;
        }
    }
}

extern "C" void kernel_launch(void* const* d_in, const int* in_sizes, int n_in,
                              void* d_out, int out_size, void* d_ws, size_t ws_size,
                              hipStream_t stream) {
    const float* in_feats = (const float*)d_in[0];
    const float* kernelw  = (const float*)d_in[1];
    const float* bias     = (const float*)d_in[2];
    const int*   imap     = (const int*)d_in[3];
    const int*   omap     = (const int*)d_in[4];
    float* out = (float*)d_out;

    char* p = (char*)d_ws;
    ushort* feats_bf = (ushort*)p;  p += (size_t)N_IN * C_IN * 2;                  // 25.6 MB
    ushort* wt_bf    = (ushort*)p;  p += (size_t)K_VOL * C_IN * C_OUT * 2;         // 216 KB
    unsigned int* cursor  = (unsigned int*)p;  p += (((size_t)NBUCKET * 4 + 63) & ~(size_t)63); // 337.5 KB
    unsigned int* records = (unsigned int*)p;  p += (size_t)NBUCKET * CAP * 4;     // 32.4 MB  (58.6 MB total, R3-proven fit)

    hipMemsetAsync(cursor, 0, (size_t)NBUCKET * 4, stream);

    cvt_kernel<<<1024, NTHREADS, 0, stream>>>(in_feats, kernelw, feats_bf, wt_bf);

    dim3 gscat((M_PAIRS + NTHREADS - 1) / NTHREADS, K_VOL);
    scatter_kernel<<<gscat, NTHREADS, 0, stream>>>(imap, omap, cursor, records);

    spconv_kernel<<<NRANGE, NTHREADS, 0, stream>>>(feats_bf, wt_bf, cursor, records, bias, out);
}

// Round 9
// 823.911 us; speedup vs baseline: 2.0273x; 1.8951x over previous
//
#include <hip/hip_runtime.h>

#define N_IN 200000
#define N_OUT 200000
#define K_VOL 27
#define M_PAIRS 100000
#define C_IN 64
#define C_OUT 64

// output privatization: each block owns RROWS output rows, accumulates in LDS fp32
#define RROWS 64
#define RSHIFT 6
#define NRANGE (N_OUT / RROWS)        // 3125 (exact)
#define NBUCKET (NRANGE * K_VOL)      // 84375 (bucket = range*27 + k)
#define CAP 96                        // fixed bucket capacity; Poisson(32) -> P(any>96) ~ 1e-14
#define ACC_PAD 68                    // acc row stride (272B), de-aliased banks
#define LDS_PAD 72                    // A-tile row stride (144B = 9x16B)
#define NTHREADS 256
#define MAXG 176                      // ngroups <= 27 * ceil(96/16) = 162
#define SCATB ((M_PAIRS + NTHREADS - 1) / NTHREADS)   // 391
#define NSCAT (SCATB * K_VOL)                         // 10557 scatter-role blocks
#define NCVTB 512                                     // cvt-role blocks

typedef __attribute__((ext_vector_type(4))) float floatx4;
typedef __attribute__((ext_vector_type(8))) short shortx8;

static __device__ __forceinline__ ushort f32_to_bf16(float f) {
    union { float f; unsigned int u; } x; x.f = f;
    unsigned int u = x.u;
    u += 0x7FFFu + ((u >> 16) & 1u);   // round-to-nearest-even
    return (ushort)(u >> 16);
}

// Fused prepass, role-split grid:
//   blocks [0, NSCAT):       direct reservation scatter (atomicAdd pos + atomicExch payload,
//                            R7-proven cross-XCD-safe record write)
//   blocks [NSCAT, +NCVTB):  grid-stride fp32->bf16 feats + transposed-weights convert
__global__ void prep_kernel(const float* __restrict__ in_feats, const float* __restrict__ w,
                            const int* __restrict__ imap, const int* __restrict__ omap,
                            ushort* __restrict__ feats_bf, ushort* __restrict__ wt_bf,
                            unsigned int* __restrict__ cursor, unsigned int* __restrict__ records) {
    const int bx  = blockIdx.x;
    const int tid = threadIdx.x;
    if (bx < NSCAT) {
        const int k = bx / SCATB;
        const int m = (bx % SCATB) * NTHREADS + tid;
        if (m < M_PAIRS) {
            const int o = omap[k * M_PAIRS + m];
            const int b = (o >> RSHIFT) * K_VOL + k;
            unsigned int pos = atomicAdd(&cursor[b], 1u);
            if (pos < CAP) {
                unsigned int g = (unsigned int)imap[k * M_PAIRS + m];
                atomicExch(&records[(unsigned int)b * CAP + pos],
                           g | ((unsigned int)(o & (RROWS - 1)) << 18));
            }
        }
    } else {
        const int g0 = (bx - NSCAT) * NTHREADS + tid;
        const int GS = NCVTB * NTHREADS;
        const int n4 = N_IN * C_IN / 4;
        for (int i = g0; i < n4; i += GS) {
            float4 v = ((const float4*)in_feats)[i];
            ushort4 o;
            o.x = f32_to_bf16(v.x); o.y = f32_to_bf16(v.y);
            o.z = f32_to_bf16(v.z); o.w = f32_to_bf16(v.w);
            ((ushort4*)feats_bf)[i] = o;
        }
        for (int idx = g0; idx < K_VOL * C_IN * C_OUT; idx += GS) {
            int k = idx >> 12; int rem = idx & 4095;
            int c = rem >> 6;  int o = rem & 63;
            wt_bf[(k << 12) + (o << 6) + c] = f32_to_bf16(w[idx]);
        }
    }
}

// Phase B: per range-block, double-buffered cooperative staging (R7-proven) + per-wave
// column-ownership accumulate: wave w owns acc cols [16w,16w+16), processes ALL groups
// of a chunk with its own B-cluster -> plain LDS read+add+write, ZERO atomics.
// Cross-quad same-(row,col) updates (duplicate output rows within a group; colbase is
// quad-independent) are serialized by 4 exec-masked phases. R8 BUG: the phase loop was
// legally collapsed by the compiler (per-thread semantics). Fix: wave_barrier between
// phases (opaque/convergent -> no collapse, no DS motion across) + volatile RMW.
__launch_bounds__(NTHREADS, 4)
__global__ void spconv_kernel(const ushort* __restrict__ feats,    // [N_IN][64] bf16
                              const ushort* __restrict__ wt,       // [K][64 o][64 c] bf16
                              const unsigned int* __restrict__ cursor,   // per-bucket counts
                              const unsigned int* __restrict__ records,  // [NBUCKET][CAP]
                              const float* __restrict__ bias,
                              float* __restrict__ out) {
    __shared__ __align__(16) float  accs[(RROWS + 1) * ACC_PAD];   // 17,680 B (+1 dummy row)
    __shared__ __align__(16) ushort Abuf[2][RROWS * LDS_PAD];      // 2 x 9,216 B
    __shared__ unsigned int  gt_s[MAXG];    // group start word-index in records
    __shared__ unsigned char gk_s[MAXG];    // group kernel-offset
    __shared__ unsigned char gv_s[MAXG];    // valid rows in group (1..16)
    __shared__ int ngroups_s;

    const int tid = threadIdx.x;
    const int bx  = blockIdx.x;

    for (int idx = tid; idx < ((RROWS + 1) * ACC_PAD) / 4; idx += NTHREADS)
        ((float4*)accs)[idx] = make_float4(0.f, 0.f, 0.f, 0.f);

    // wave 0 builds the group table (k ascending; groups are 16-padded -> single-k each)
    if (tid < 64) {
        int kk = tid;
        int nt = 0; unsigned int cnt = 0, base = 0;
        if (kk < K_VOL) {
            cnt = cursor[bx * K_VOL + kk];
            if (cnt > CAP) cnt = CAP;
            nt   = (int)((cnt + 15u) >> 4);
            base = (unsigned int)(bx * K_VOL + kk) * CAP;
        }
        int x = nt;
        #pragma unroll
        for (int d = 1; d < 32; d <<= 1) {
            int y = __shfl_up(x, d);
            if (tid >= d) x += y;
        }
        int gb = x - nt;
        for (int j = 0; j < nt; ++j) {
            int e = gb + j;
            if (e < MAXG) {
                gt_s[e] = base + (unsigned int)(j << 4);
                gk_s[e] = (unsigned char)kk;
                gv_s[e] = (unsigned char)((j == nt - 1) ? (cnt - (unsigned int)(j << 4)) : 16u);
            }
        }
        if (kk == K_VOL - 1) ngroups_s = (x < MAXG) ? x : MAXG;
    }
    __syncthreads();

    const int ngroups = ngroups_s;
    const int nchunks = (ngroups + 3) >> 2;        // 4 groups (64 rows) per chunk

    const int wave = tid >> 6;
    const int lane = tid & 63;
    const int quad = lane >> 4;
    const int l16  = lane & 15;
    const int colbase = wave * 16 + l16;           // this wave's owned column (per lane)

    // staging map: thread stages rows row0 and row0+32 of the chunk, 16B at column ch0*8
    const int row0 = tid >> 3;        // 0..31
    const int row1 = row0 + 32;       // 32..63
    const int ch0  = tid & 7;

    // prologue: stage chunk 0 into buf 0
    if (nchunks > 0) {
        int gA = row0 >> 4;
        if (gA < ngroups) {
            unsigned int rec = records[gt_s[gA] + (row0 & 15)];
            shortx8 v = *(const shortx8*)&feats[((rec & 0x3FFFFu) << 6) + ch0 * 8];
            *(shortx8*)&Abuf[0][row0 * LDS_PAD + ch0 * 8] = v;
        }
        int gB = row1 >> 4;
        if (gB < ngroups) {
            unsigned int rec = records[gt_s[gB] + (row1 & 15)];
            shortx8 v = *(const shortx8*)&feats[((rec & 0x3FFFFu) << 6) + ch0 * 8];
            *(shortx8*)&Abuf[0][row1 * LDS_PAD + ch0 * 8] = v;
        }
    }
    __syncthreads();

    int kcur = -1;
    shortx8 bw0, bw1;                 // this wave's B cluster only (8 VGPRs)

    for (int cj = 0; cj < nchunks; ++cj) {
        const int cur = cj & 1, nxt = cur ^ 1;

        // (a) issue next chunk's gather loads early (write after compute, T14 split)
        shortx8 n0, n1; bool h0 = false, h1 = false;
        if (cj + 1 < nchunks) {
            int gA = (cj + 1) * 4 + (row0 >> 4);
            if (gA < ngroups) {
                unsigned int rec = records[gt_s[gA] + (row0 & 15)];
                n0 = *(const shortx8*)&feats[((rec & 0x3FFFFu) << 6) + ch0 * 8];
                h0 = true;
            }
            int gB = (cj + 1) * 4 + (row1 >> 4);
            if (gB < ngroups) {
                unsigned int rec = records[gt_s[gB] + (row1 & 15)];
                n1 = *(const shortx8*)&feats[((rec & 0x3FFFFu) << 6) + ch0 * 8];
                h1 = true;
            }
        }

        // (b) compute: this wave processes ALL 4 groups, its own column cluster
        for (int gl = 0; gl < 4; ++gl) {
            const int gidx = cj * 4 + gl;
            if (gidx >= ngroups) break;            // uniform
            const int k = (int)gk_s[gidx];
            if (k != kcur) {                       // wave-uniform, k ascending (~27 reloads)
                kcur = k;
                const ushort* wp = &wt[(kcur << 12) + colbase * 64 + quad * 8];
                bw0 = *(const shortx8*)(wp);
                bw1 = *(const shortx8*)(wp + 32);
            }
            const unsigned int t = gt_s[gidx];
            const int4 rr = *(const int4*)&records[t + (quad << 2)];   // 16B aligned
            const int vld = (int)gv_s[gidx];

            const ushort* ap = &Abuf[cur][(gl * 16 + l16) * LDS_PAD];
            const shortx8 a0 = *(const shortx8*)&ap[quad * 8];
            const shortx8 a1 = *(const shortx8*)&ap[32 + quad * 8];

            floatx4 acc = {0.f, 0.f, 0.f, 0.f};
            acc = __builtin_amdgcn_mfma_f32_16x16x32_bf16(a0, bw0, acc, 0, 0, 0);
            acc = __builtin_amdgcn_mfma_f32_16x16x32_bf16(a1, bw1, acc, 0, 0, 0);

            // C rows = quad*4 + r; rows past valid count -> dummy row RROWS (discarded)
            const int q4 = quad << 2;
            const int ra = (q4 + 0 < vld) ? ((rr.x >> 18) & (RROWS - 1)) : RROWS;
            const int rb = (q4 + 1 < vld) ? ((rr.y >> 18) & (RROWS - 1)) : RROWS;
            const int rc = (q4 + 2 < vld) ? ((rr.z >> 18) & (RROWS - 1)) : RROWS;
            const int rd = (q4 + 3 < vld) ? ((rr.w >> 18) & (RROWS - 1)) : RROWS;

            // Quad-serialized plain RMW. wave_barrier = convergent + side-effecting:
            // the guard loop cannot be collapsed per-thread, DS ops cannot be moved
            // across phases; per-wave DS ops execute in issue order -> phases are
            // truly serial. volatile pins each read-add-write.
            volatile float* av = accs;
            #pragma unroll
            for (int s = 0; s < 4; ++s) {
                if (quad == s) {
                    av[ra * ACC_PAD + colbase] += acc[0];
                    av[rb * ACC_PAD + colbase] += acc[1];
                    av[rc * ACC_PAD + colbase] += acc[2];
                    av[rd * ACC_PAD + colbase] += acc[3];
                }
                __builtin_amdgcn_wave_barrier();
            }
        }

        // (c) write the prefetched chunk into the other buffer, then one barrier
        if (h0) *(shortx8*)&Abuf[nxt][row0 * LDS_PAD + ch0 * 8] = n0;
        if (h1) *(shortx8*)&Abuf[nxt][row1 * LDS_PAD + ch0 * 8] = n1;
        __syncthreads();
    }

    __syncthreads();   // all LDS ops compiler-visible -> standard drain suffices

    // write out 64 rows x 64 ch, bias fused, each output line written exactly once
    const int r0 = bx * RROWS;
    #pragma unroll
    for (int it = 0; it < (RROWS * 16) / NTHREADS; ++it) {
        int idx  = tid + it * NTHREADS;      // 0..1023 float4 slots
        int row  = idx >> 4;
        int c4   = idx & 15;
        int orow = r0 + row;
        if (orow < N_OUT) {
            float4 v = *(float4*)&accs[row * ACC_PAD + c4 * 4];
            const float4 bb = *(const float4*)&bias[c4 * 4];
            v.x += bb.x; v.y += bb.y; v.z += bb.z; v.w += bb.w;
            *(float4*)&out[(orow << 6) + c4 * 4] = v;
        }
    }
}

extern "C" void kernel_launch(void* const* d_in, const int* in_sizes, int n_in,
                              void* d_out, int out_size, void* d_ws, size_t ws_size,
                              hipStream_t stream) {
    const float* in_feats = (const float*)d_in[0];
    const float* kernelw  = (const float*)d_in[1];
    const float* bias     = (const float*)d_in[2];
    const int*   imap     = (const int*)d_in[3];
    const int*   omap     = (const int*)d_in[4];
    float* out = (float*)d_out;

    char* p = (char*)d_ws;
    ushort* feats_bf = (ushort*)p;  p += (size_t)N_IN * C_IN * 2;                  // 25.6 MB
    ushort* wt_bf    = (ushort*)p;  p += (size_t)K_VOL * C_IN * C_OUT * 2;         // 216 KB
    unsigned int* cursor  = (unsigned int*)p;  p += (((size_t)NBUCKET * 4 + 63) & ~(size_t)63); // 337.5 KB
    unsigned int* records = (unsigned int*)p;  p += (size_t)NBUCKET * CAP * 4;     // 32.4 MB (58.6 MB total, proven fit)

    hipMemsetAsync(cursor, 0, (size_t)NBUCKET * 4, stream);

    prep_kernel<<<NSCAT + NCVTB, NTHREADS, 0, stream>>>(
        in_feats, kernelw, imap, omap, feats_bf, wt_bf, cursor, records);

    spconv_kernel<<<NRANGE, NTHREADS, 0, stream>>>(feats_bf, wt_bf, cursor, records, bias, out);
}